// Round 1
// baseline (183.245 us; speedup 1.0000x reference)
//
#include <hip/hip_runtime.h>

#define H_OUT 8
#define W_OUT 8
#define MAXG 4

__global__ __launch_bounds__(256) void ordered_roi_kernel(
    const float* __restrict__ feats,        // [B,C,H,W]
    const int*   __restrict__ batch_idxs,   // [N]
    const int*   __restrict__ starts,       // [N,2]
    const int*   __restrict__ goals,        // [N,2]
    float*       __restrict__ out,          // [N,C,8,8]
    int C, int H, int W)
{
    const int n   = blockIdx.x;
    const int tid = threadIdx.x;

    // ---- per-box parameters (computed redundantly per thread; cheap) ----
    const float s0 = (float)starts[2 * n + 0];
    const float s1 = (float)starts[2 * n + 1];
    const float g0 = (float)goals[2 * n + 0];
    const float g1 = (float)goals[2 * n + 1];

    const float y_min = fminf(s0, g0), y_max = fmaxf(s0, g0);
    const float x_min = fminf(s1, g1), x_max = fmaxf(s1, g1);
    const bool  y_rev = s0 > g0;
    const bool  x_rev = s1 > g1;

    const float start_h = y_min - 0.5f;
    const float start_w = x_min - 0.5f;
    const float bin_h = (y_max - y_min) / (float)H_OUT;
    const float bin_w = (x_max - x_min) / (float)W_OUT;
    const int   gh = (int)ceilf(bin_h);
    const int   gw = (int)ceilf(bin_w);
    const float count     = fmaxf((float)(gh * gw), 1.0f);
    const float inv_count = 1.0f / count;

    // ---- per-axis sample tables in LDS: [axis][bin*MAXG + i] ----
    __shared__ int   s_lo[2][H_OUT * MAXG];
    __shared__ int   s_hi[2][H_OUT * MAXG];
    __shared__ float s_w0[2][H_OUT * MAXG];
    __shared__ float s_w1[2][H_OUT * MAXG];

    if (tid < 64) {
        const int axis = tid >> 5;      // 0 = y, 1 = x
        const int k    = tid & 31;
        const int ph   = k >> 2;        // output bin 0..7
        const int i    = k & 3;         // sample 0..3
        const float start = axis ? start_w : start_h;
        const float bin   = axis ? bin_w  : bin_h;
        const int   grid  = axis ? gw     : gh;
        const float size  = axis ? (float)W : (float)H;
        const float gsafe = (float)(grid > 1 ? grid : 1);
        const float pos = start + (float)ph * bin + ((float)i + 0.5f) * (bin / gsafe);
        const bool  valid = (pos >= -1.0f) && (pos <= size) && (i < grid);
        const float p  = fminf(fmaxf(pos, 0.0f), size - 1.0f);
        const int   lo = (int)floorf(p);
        const int   hi = min(lo + 1, (int)size - 1);
        const float l  = p - (float)lo;
        const float vf = valid ? 1.0f : 0.0f;
        s_lo[axis][k] = lo;
        s_hi[axis][k] = hi;
        s_w0[axis][k] = (1.0f - l) * vf;
        s_w1[axis][k] = l * vf;
    }
    __syncthreads();

    const int b = batch_idxs[n];
    const float* __restrict__ fb = feats + (size_t)b * C * H * W;
    float*       __restrict__ ob = out   + (size_t)n * C * (H_OUT * W_OUT);
    const int total = C * H_OUT * W_OUT;

    for (int idx = tid; idx < total; idx += 256) {
        const int c  = idx >> 6;
        const int yx = idx & 63;
        const int y  = yx >> 3;
        const int x  = yx & 7;

        // flip-gather source bin (faithful to the reference's table quirk):
        //   case (0,0): identity
        //   case x_rev XOR y_rev: src = y*8 + (7-y)   (px depends on y!)
        //   case both: src = (7-y)*8 + x
        int py, px;
        if (y_rev && x_rev)      { py = H_OUT - 1 - y; px = x; }
        else if (y_rev || x_rev) { py = y;             px = W_OUT - 1 - y; }
        else                     { py = y;             px = x; }

        const float* __restrict__ fc = fb + (size_t)c * H * W;
        float acc = 0.0f;
        #pragma unroll
        for (int iy = 0; iy < MAXG; ++iy) {
            const int   ky  = py * MAXG + iy;
            const float wy0 = s_w0[0][ky];
            const float wy1 = s_w1[0][ky];
            if (wy0 == 0.0f && wy1 == 0.0f) continue;   // invalid sample -> +0
            const float* __restrict__ r0 = fc + s_lo[0][ky] * W;
            const float* __restrict__ r1 = fc + s_hi[0][ky] * W;
            #pragma unroll
            for (int ix = 0; ix < MAXG; ++ix) {
                const int   kx  = px * MAXG + ix;
                const float wx0 = s_w0[1][kx];
                const float wx1 = s_w1[1][kx];
                const float v0 = wx0 * r0[s_lo[1][kx]] + wx1 * r0[s_hi[1][kx]];
                const float v1 = wx0 * r1[s_lo[1][kx]] + wx1 * r1[s_hi[1][kx]];
                acc += wy0 * v0 + wy1 * v1;
            }
        }
        ob[idx] = acc * inv_count;
    }
}

extern "C" void kernel_launch(void* const* d_in, const int* in_sizes, int n_in,
                              void* d_out, int out_size, void* d_ws, size_t ws_size,
                              hipStream_t stream) {
    const float* feats      = (const float*)d_in[0];
    const int*   batch_idxs = (const int*)d_in[1];
    const int*   starts     = (const int*)d_in[2];
    const int*   goals      = (const int*)d_in[3];
    float*       out        = (float*)d_out;

    const int N = in_sizes[1];                       // 1024
    const int H = 32, W = 32;
    const int C = out_size / (N * H_OUT * W_OUT);    // 64

    ordered_roi_kernel<<<N, 256, 0, stream>>>(feats, batch_idxs, starts, goals,
                                              out, C, H, W);
}

// Round 3
// 82.746 us; speedup vs baseline: 2.2145x; 2.2145x over previous
//
#include <hip/hip_runtime.h>

#define H_OUT 8
#define W_OUT 8
#define MAXG 4
#define CCHUNK 8   // channels per block

// Separable ROI-align: rois[c] = Wy * F[c] * Wx^T, per box, then flip-gather.
// Block = (box n, channel-chunk of 8). 256 threads.
//  Stage A: tmp[c][py][x] = sum_iy wy * F[c][ylo/yhi][x]   (coalesced global rows)
//  Stage B: out[c][py][px] = sum_ix wx * tmp[c][py][xlo/xhi] (LDS, padded pitch)
__global__ __launch_bounds__(256) void ordered_roi_kernel(
    const float* __restrict__ feats,        // [B,C,32,32]
    const int*   __restrict__ batch_idxs,   // [N]
    const int*   __restrict__ starts,       // [N,2]
    const int*   __restrict__ goals,        // [N,2]
    float*       __restrict__ out,          // [N,C,8,8]
    int C, int CG)                          // CG = C / CCHUNK
{
    const int bx  = blockIdx.x;
    const int n   = bx / CG;
    const int cg  = bx - n * CG;
    const int tid = threadIdx.x;

    // ---- per-box params (uniform -> scalarized by compiler) ----
    const float s0 = (float)starts[2 * n + 0];
    const float s1 = (float)starts[2 * n + 1];
    const float g0 = (float)goals[2 * n + 0];
    const float g1 = (float)goals[2 * n + 1];
    const float y_min = fminf(s0, g0), y_max = fmaxf(s0, g0);
    const float x_min = fminf(s1, g1), x_max = fmaxf(s1, g1);
    const bool  y_rev = s0 > g0;
    const bool  x_rev = s1 > g1;
    const float start_h = y_min - 0.5f;
    const float start_w = x_min - 0.5f;
    const float bin_h = (y_max - y_min) / (float)H_OUT;
    const float bin_w = (x_max - x_min) / (float)W_OUT;
    const int   gh = (int)ceilf(bin_h);
    const int   gw = (int)ceilf(bin_w);
    const float inv_count = 1.0f / fmaxf((float)(gh * gw), 1.0f);

    // ---- per-axis sample tables ----
    __shared__ int   s_lo[2][H_OUT * MAXG];
    __shared__ int   s_hi[2][H_OUT * MAXG];
    __shared__ float s_w0[2][H_OUT * MAXG];
    __shared__ float s_w1[2][H_OUT * MAXG];
    // y-reduced tmp, padded x-pitch 33 -> stage-B bank = (py + xlo) % 32
    __shared__ float s_t[CCHUNK][H_OUT][33];

    if (tid < 64) {
        const int axis = tid >> 5;      // 0 = y, 1 = x
        const int k    = tid & 31;
        const int ph   = k >> 2;
        const int i    = k & 3;
        const float start = axis ? start_w : start_h;
        const float bin   = axis ? bin_w  : bin_h;
        const int   grid  = axis ? gw     : gh;
        const float size  = 32.0f;
        const float gsafe = (float)(grid > 1 ? grid : 1);
        const float pos = start + (float)ph * bin + ((float)i + 0.5f) * (bin / gsafe);
        const bool  valid = (pos >= -1.0f) && (pos <= size) && (i < grid);
        const float p  = fminf(fmaxf(pos, 0.0f), size - 1.0f);
        const int   lo = (int)floorf(p);
        const int   hi = min(lo + 1, 31);
        const float l  = p - (float)lo;
        const float vf = valid ? 1.0f : 0.0f;
        s_lo[axis][k] = lo;
        s_hi[axis][k] = hi;
        s_w0[axis][k] = (1.0f - l) * vf;
        s_w1[axis][k] = l * vf;
    }
    __syncthreads();

    // ================= Stage A: y-reduction =================
    // thread -> (py_a, x_a), constant across the 8 channels.
    const int py_a = (tid >> 5) & 7;
    const int x_a  = tid & 31;

    int   yloR[MAXG], yhiR[MAXG];
    float wy0R[MAXG], wy1R[MAXG];
    #pragma unroll
    for (int iy = 0; iy < MAXG; ++iy) {
        const int ky = py_a * MAXG + iy;
        yloR[iy] = s_lo[0][ky] * 32 + x_a;
        yhiR[iy] = s_hi[0][ky] * 32 + x_a;
        wy0R[iy] = s_w0[0][ky];
        wy1R[iy] = s_w1[0][ky];
    }

    const int b = batch_idxs[n];
    const float* __restrict__ fb = feats + ((size_t)b * C + (size_t)cg * CCHUNK) * 1024;

    #pragma unroll
    for (int c = 0; c < CCHUNK; ++c) {
        const float* __restrict__ fc = fb + c * 1024;
        float acc = 0.0f;
        #pragma unroll
        for (int iy = 0; iy < MAXG; ++iy) {
            if (iy < gh) {   // uniform branch; weights already carry pos-validity
                acc += wy0R[iy] * fc[yloR[iy]] + wy1R[iy] * fc[yhiR[iy]];
            }
        }
        s_t[c][py_a][x_a] = acc;
    }
    __syncthreads();

    // ================= Stage B: x-reduction + flip + write =================
    // outputs o = {tid, tid+256}; o -> (c = o>>6, y = (o>>3)&7, x = o&7)
    const int yx = tid & 63;
    const int y  = yx >> 3;
    const int xo = yx & 7;
    const int c0 = tid >> 6;   // 0..3 ; second output uses c0+4

    // flip-gather source bin (faithful reference-table quirk):
    //  none: (y,x) ; x_rev XOR y_rev: (y, 7-y) ; both: (7-y, x)
    int py, px;
    if (y_rev && x_rev)      { py = H_OUT - 1 - y; px = xo; }
    else if (y_rev || x_rev) { py = y;             px = W_OUT - 1 - y; }
    else                     { py = y;             px = xo; }

    float acc0 = 0.0f, acc1 = 0.0f;
    #pragma unroll
    for (int ix = 0; ix < MAXG; ++ix) {
        if (ix < gw) {   // uniform branch
            const int   kx  = px * MAXG + ix;
            const int   xlo = s_lo[1][kx];
            const int   xhi = s_hi[1][kx];
            const float wx0 = s_w0[1][kx];
            const float wx1 = s_w1[1][kx];
            acc0 += wx0 * s_t[c0][py][xlo]     + wx1 * s_t[c0][py][xhi];
            acc1 += wx0 * s_t[c0 + 4][py][xlo] + wx1 * s_t[c0 + 4][py][xhi];
        }
    }

    float* __restrict__ ob = out + ((size_t)n * C + (size_t)cg * CCHUNK) * (H_OUT * W_OUT);
    ob[tid]       = acc0 * inv_count;
    ob[tid + 256] = acc1 * inv_count;
}

extern "C" void kernel_launch(void* const* d_in, const int* in_sizes, int n_in,
                              void* d_out, int out_size, void* d_ws, size_t ws_size,
                              hipStream_t stream) {
    const float* feats      = (const float*)d_in[0];
    const int*   batch_idxs = (const int*)d_in[1];
    const int*   starts     = (const int*)d_in[2];
    const int*   goals      = (const int*)d_in[3];
    float*       out        = (float*)d_out;

    const int N  = in_sizes[1];                       // 1024
    const int C  = out_size / (N * H_OUT * W_OUT);    // 64
    const int CG = C / CCHUNK;                        // 8

    ordered_roi_kernel<<<N * CG, 256, 0, stream>>>(feats, batch_idxs, starts, goals,
                                                   out, C, CG);
}